// Round 19
// baseline (235.863 us; speedup 1.0000x reference)
//
#include <hip/hip_runtime.h>
#include <hip/hip_bf16.h>

#define T_DIM 4096
#define B_DIM 32
#define I_DIM 512
#define O_DIM 512
#define M_DIM (T_DIM * B_DIM)   // 131072
#define PARAM 0.1f
#define ISCALE 1.1111112f       // 1/(1-p)

#define STRIP 32
#define TAPS 8                  // p^8 = 1e-8 << bf16 eps

#define BM 256
#define BN 256
#define BK 64
#define NK (I_DIM / BK)         // 8

typedef __attribute__((ext_vector_type(8))) short bf16x8;
typedef __attribute__((ext_vector_type(4))) float f32x4;

__device__ __forceinline__ unsigned short f2bf(float f) {
    union { __hip_bfloat16 b; unsigned short u; } cv;
    cv.b = __float2bfloat16(f);
    return cv.u;
}

// --- W fp32 -> bf16 (0.5 MB, ws offset 0) ---
__global__ __launch_bounds__(256) void wcvt_kernel(const float* __restrict__ W,
                                                   unsigned short* __restrict__ Wb) {
    const int i = (blockIdx.x * 256 + threadIdx.x) * 4;
    f32x4 v = *(const f32x4*)(W + i);
    ushort4 o;
    o.x = f2bf(v[0]); o.y = f2bf(v[1]); o.z = f2bf(v[2]); o.w = f2bf(v[3]);
    *(ushort4*)(Wb + i) = o;
}

// --- EMA over raw X (linearity: EMA(XW+b) = EMA(X)W + s[t]*b). Strip-parallel,
// TAPS warm-up reads raw X; bf16 output compacted into d_ws. Near roofline. ---
__global__ __launch_bounds__(256) void xema_kernel(const float* __restrict__ X,
                                                   unsigned short* __restrict__ Xv) {
    const int s   = blockIdx.x >> 4;                 // strip 0..127
    const int blk = blockIdx.x & 15;
    const int col = (blk * 256 + threadIdx.x) * 4;
    const int t0  = s * STRIP;
    const int b   = col >> 9;
    const int o   = col & 511;

    const float* xin = X + (size_t)t0 * 16384 + col;
    unsigned short* xout = Xv + (size_t)(t0 * 32 + b) * 512 + o;

    f32x4 v = {0.f, 0.f, 0.f, 0.f};
    if (s > 0) {
        const float* w = xin - (size_t)TAPS * 16384;
        #pragma unroll
        for (int j = 0; j < TAPS; ++j)
            v = PARAM * v + *(const f32x4*)(w + (size_t)j * 16384);
    }

    f32x4 bufA[4], bufB[4];
    #pragma unroll
    for (int j = 0; j < 4; ++j) bufA[j] = *(const f32x4*)(xin + (size_t)j * 16384);

    #pragma unroll
    for (int i = 0; i < STRIP; i += 8) {
        #pragma unroll
        for (int j = 0; j < 4; ++j)
            bufB[j] = *(const f32x4*)(xin + (size_t)(i + 4 + j) * 16384);
        #pragma unroll
        for (int j = 0; j < 4; ++j) {
            v = PARAM * v + bufA[j];
            ushort4 pk; pk.x = f2bf(v[0]); pk.y = f2bf(v[1]); pk.z = f2bf(v[2]); pk.w = f2bf(v[3]);
            *(ushort4*)(xout + (size_t)(i + j) * 16384) = pk;
        }
        if (i + 8 < STRIP) {
            #pragma unroll
            for (int j = 0; j < 4; ++j)
                bufA[j] = *(const f32x4*)(xin + (size_t)(i + 8 + j) * 16384);
        }
        #pragma unroll
        for (int j = 0; j < 4; ++j) {
            v = PARAM * v + bufB[j];
            ushort4 pk; pk.x = f2bf(v[0]); pk.y = f2bf(v[1]); pk.z = f2bf(v[2]); pk.w = f2bf(v[3]);
            *(ushort4*)(xout + (size_t)(i + 4 + j) * 16384) = pk;
        }
    }
}

// --- GEMM: m230-V0 replica — 256x256 tile, BK=64, DOUBLE-buffered LDS
// (128KB -> 1 block/CU), simple 2-phase loop: {STAGE(next buf) -> ds_read +
// 64 MFMA/wave on current -> __syncthreads}. The barrier's vmcnt(0) drains
// loads that flew for a FULL compute phase (~1000cy issue > ~600cy L2
// latency) -> drain ~0, no inter-block overlap needed. 512 thr / 8 waves,
// wave-tile 128x64 (acc 8x4). Pre-swizzled gload_lds (involution c^(r&7));
// conflict-free swizzled ds_read; swapped-operand MFMA -> Y^T frags ->
// float4 epilogue. XCD grouping: bn-pair adjacent per XCD. ---
__global__ __launch_bounds__(512, 2) void gemm_kernel(const unsigned short* __restrict__ Xv,
                                                      const unsigned short* __restrict__ Wb,
                                                      const float* __restrict__ bias,
                                                      float* __restrict__ Y) {
    __shared__ __align__(16) short As[2][BM * BK];   // 32 KB x2
    __shared__ __align__(16) short Bs[2][BN * BK];   // 32 KB x2

    const int tid  = threadIdx.x;
    const int lane = tid & 63;
    const int wave = tid >> 6;        // 0..7
    const int wm   = wave >> 2;       // 0..1 (128-row half)
    const int wn   = wave & 3;        // 0..3 (64-col quarter)

    // 1024 blocks (%8==0): xcd = bid&7; bn toggles fastest within an XCD chunk.
    const int bid  = blockIdx.x;
    const int swz  = (bid & 7) * 128 + (bid >> 3);
    const int bn   = swz & 1;
    const int mt   = swz >> 1;                    // 0..511
    const int row0 = mt * BM;
    const int col0 = bn * BN;

    // Staging: 16B chunks, 8 per 128B row; 4 row-sets of 64. r&7 = (tid>>3)&7
    // for every set -> swizzled source chunk cs is per-thread constant.
    const int cs = (tid & 7) ^ ((tid >> 3) & 7);
    const unsigned short* aSrc = Xv + (size_t)(row0 + (tid >> 3)) * 512 + cs * 8;
    const unsigned short* bSrc = Wb + (size_t)(col0 + (tid >> 3)) * 512 + cs * 8;

    #define STAGE(d, kt)                                                              \
        do {                                                                          \
            _Pragma("unroll")                                                         \
            for (int s_ = 0; s_ < 4; ++s_)                                            \
                __builtin_amdgcn_global_load_lds(                                     \
                    (const __attribute__((address_space(1))) unsigned int*)(aSrc + (size_t)s_ * 64 * 512 + (kt) * 64), \
                    (__attribute__((address_space(3))) unsigned int*)(&As[d][0] + (s_ * 512 + tid) * 8),              \
                    16, 0, 0);                                                        \
            _Pragma("unroll")                                                         \
            for (int s_ = 0; s_ < 4; ++s_)                                            \
                __builtin_amdgcn_global_load_lds(                                     \
                    (const __attribute__((address_space(1))) unsigned int*)(bSrc + (size_t)s_ * 64 * 512 + (kt) * 64), \
                    (__attribute__((address_space(3))) unsigned int*)(&Bs[d][0] + (s_ * 512 + tid) * 8),              \
                    16, 0, 0);                                                        \
        } while (0)

    f32x4 acc[8][4] = {};   // [mf][nf], swapped-operand: reg j = 4 consecutive Y-cols

    STAGE(0, 0);
    __syncthreads();   // tile 0 ready

    for (int ks = 0; ks < NK; ++ks) {
        const int cur = ks & 1;
        if (ks < NK - 1)
            STAGE(cur ^ 1, ks + 1);   // issue BEFORE compute: flies during MFMAs

        #pragma unroll
        for (int kk = 0; kk < 2; ++kk) {
            const int cc = kk * 4 + (lane >> 4);
            bf16x8 a_[8], b_[4];
            #pragma unroll
            for (int mf = 0; mf < 8; ++mf) {
                const int r = wm * 128 + mf * 16 + (lane & 15);
                a_[mf] = *(const bf16x8*)((const char*)&As[cur][0] + r * 128 + ((cc ^ (r & 7)) << 4));
            }
            #pragma unroll
            for (int nf = 0; nf < 4; ++nf) {
                const int r = wn * 64 + nf * 16 + (lane & 15);
                b_[nf] = *(const bf16x8*)((const char*)&Bs[cur][0] + r * 128 + ((cc ^ (r & 7)) << 4));
            }
            #pragma unroll
            for (int mf = 0; mf < 8; ++mf)
                #pragma unroll
                for (int nf = 0; nf < 4; ++nf)
                    acc[mf][nf] = __builtin_amdgcn_mfma_f32_16x16x32_bf16(
                        b_[nf], a_[mf], acc[mf][nf], 0, 0, 0);   // swapped -> Y^T frag
        }
        __syncthreads();   // drains the prefetch (already ~fully flown) + LDS reuse
    }

    // Epilogue: Y = acc + s[t]*bias, float4 stores. t = grow>>5; within the
    // 128-row wave tile, t offset = mf>>1.
    float sc4[4];
    #pragma unroll
    for (int tt = 0; tt < 4; ++tt) {
        const int t_ = ((row0 + wm * 128) >> 5) + tt;
        sc4[tt] = (1.0f - __expf(-2.3025851f * (float)(t_ + 1))) * ISCALE;
    }
    f32x4 bvv[4];
    #pragma unroll
    for (int nf = 0; nf < 4; ++nf)
        bvv[nf] = *(const f32x4*)(bias + col0 + wn * 64 + nf * 16 + ((lane >> 4) << 2));

    #pragma unroll
    for (int mf = 0; mf < 8; ++mf) {
        const int grow = row0 + wm * 128 + mf * 16 + (lane & 15);
        const float sc = sc4[mf >> 1];
        #pragma unroll
        for (int nf = 0; nf < 4; ++nf) {
            const int gcol = col0 + wn * 64 + nf * 16 + ((lane >> 4) << 2);
            f32x4 out;
            #pragma unroll
            for (int e = 0; e < 4; ++e) out[e] = acc[mf][nf][e] + sc * bvv[nf][e];
            *(f32x4*)(Y + (size_t)grow * O_DIM + gcol) = out;
        }
    }
}

extern "C" void kernel_launch(void* const* d_in, const int* in_sizes, int n_in,
                              void* d_out, int out_size, void* d_ws, size_t ws_size,
                              hipStream_t stream) {
    const float* X    = (const float*)d_in[0];
    const float* W    = (const float*)d_in[1];
    const float* bias = (const float*)d_in[2];
    float* Y = (float*)d_out;
    unsigned short* Wb = (unsigned short*)d_ws;                       // 512 KB
    unsigned short* Xv = (unsigned short*)((char*)d_ws + (1 << 20));  // 134 MB

    wcvt_kernel<<<dim3(O_DIM * I_DIM / (256 * 4)), dim3(256), 0, stream>>>(W, Wb);
    xema_kernel<<<dim3((T_DIM / STRIP) * 16), dim3(256), 0, stream>>>(X, Xv);
    gemm_kernel<<<dim3((M_DIM / BM) * (O_DIM / BN)), dim3(512), 0, stream>>>(Xv, Wb, bias, Y);
}